// Round 5
// baseline (188.804 us; speedup 1.0000x reference)
//
#include <hip/hip_runtime.h>

// GAE: (B=8192, T=256, A=4, 1) fp32.
// g[t] = d[t] + c[t]*g[t+1], c = GAMMA*LMBDA*(1-term), g[T]=0
// adv = g, ret = g + v. d_out = [adv | ret] flat.
//
// Round-5 = round-4 with the compile fix (nontemporal stores need a native
// clang vector type, not HIP's float4 class):
//  - LDS 16 KB/block: terminated-flag packed into bit 0 of d's mantissa.
//  - Wave-local LDS fences instead of __syncthreads (per-wave buffers, no
//    cross-wave deps -> no convoy).
//  - __launch_bounds__(256,8): 8 blocks/CU target, 32 waves/CU.
//  - Nontemporal vec4 stores (outputs never re-read).

#define GAMMA 0.99f
#define LMBDA 0.95f
#define GL    (0.99f * 0.95f)

constexpr int T = 256;

typedef float vfloat4 __attribute__((ext_vector_type(4)));

static __device__ __forceinline__ void wave_lds_fence() {
    // Orders this wave's LDS ops (s_waitcnt lgkmcnt(0)) without s_barrier.
    __builtin_amdgcn_fence(__ATOMIC_SEQ_CST, "workgroup");
}

__global__ __launch_bounds__(256, 8) void gae_scan_kernel(
    const float* __restrict__ reward,
    const float* __restrict__ terminated,
    const float* __restrict__ value,
    const float* __restrict__ next_value,
    float* __restrict__ adv_out,
    float* __restrict__ ret_out)
{
    __shared__ float buf[4][16 * 64];   // 16 KB: packed d (bit0 = nd), then g

    const int w    = threadIdx.x >> 6;   // wave id in block = local sequence
    const int lane = threadIdx.x & 63;
    const int b    = blockIdx.x * 4 + w;
    float* __restrict__ P = buf[w];      // private to this wave

    // ---- Phase A: coalesced load, compute packed d, transpose to LDS ----
    vfloat4 v4[4];
#pragma unroll
    for (int q = 0; q < 4; ++q) {
        const int f  = 64 * q + lane;       // float4 index = timestep t
        const int gi = b * 256 + f;
        const vfloat4 r  = ((const vfloat4*)reward)[gi];
        const vfloat4 tm = ((const vfloat4*)terminated)[gi];
        const vfloat4 v  = ((const vfloat4*)value)[gi];
        const vfloat4 nv = ((const vfloat4*)next_value)[gi];
        v4[q] = v;

        const int s   = 255 - f;            // scan index (reversed time)
        const int row = s & 15;
        const int col = (4 * (s >> 4) + 4 * row) & 63;   // swizzled 4*tc

        vfloat4 p;
#pragma unroll
        for (int c0 = 0; c0 < 4; ++c0) {
            float dd = r[c0] + GAMMA * nv[c0] * (1.0f - tm[c0]) - v[c0];
            // bit0 = not-done flag (1 ulp of d sacrificed)
            p[c0] = __uint_as_float((__float_as_uint(dd) & ~1u) |
                                    (tm[c0] == 0.0f ? 1u : 0u));
        }
        *((vfloat4*)&P[row * 64 + col]) = p;
    }
    wave_lds_fence();

    // ---- Phase B: thread (tc,a) owns 16 consecutive scan steps ----
    const int tc = lane >> 2;    // time chunk 0..15
    const int a  = lane & 3;     // agent channel

    float d[16], c[16];
#pragma unroll
    for (int j = 0; j < 16; ++j) {
        const int col = (4 * tc + 4 * j + a) & 63;
        const unsigned u = __float_as_uint(P[j * 64 + col]);
        c[j] = (u & 1u) ? GL : 0.0f;
        d[j] = __uint_as_float(u & ~1u);
    }

    // Local chunk composite: out = D + K * in.
    float D = d[0], K = c[0];
#pragma unroll
    for (int j = 1; j < 16; ++j) { D = d[j] + c[j] * D; K = c[j] * K; }

    // Inclusive shuffle scan over tc (lane stride 4): 4 steps.
#pragma unroll
    for (int s2 = 1; s2 < 16; s2 <<= 1) {
        const float pD = __shfl_up(D, (unsigned)(4 * s2), 64);
        const float pK = __shfl_up(K, (unsigned)(4 * s2), 64);
        if (tc >= s2) { D = D + K * pD; K = K * pK; }
    }

    // Exclusive prefix = state entering this chunk.
    float x = __shfl_up(D, 4u, 64);
    if (tc == 0) x = 0.0f;

    // Replay chunk, write g back into the same buffer (reads already in regs).
    float g = x;
#pragma unroll
    for (int j = 0; j < 16; ++j) {
        g = d[j] + c[j] * g;
        const int col = (4 * tc + 4 * j + a) & 63;
        P[j * 64 + col] = g;
    }
    wave_lds_fence();

    // ---- Phase C: transpose-read g, coalesced nontemporal vec4 stores ----
#pragma unroll
    for (int q = 0; q < 4; ++q) {
        const int f   = 64 * q + lane;
        const int s   = 255 - f;
        const int row = s & 15;
        const int col = (4 * (s >> 4) + 4 * row) & 63;
        const vfloat4 g4 = *((const vfloat4*)&P[row * 64 + col]);

        const int gi = b * 256 + f;
        __builtin_nontemporal_store(g4, &((vfloat4*)adv_out)[gi]);
        const vfloat4 rt = g4 + v4[q];
        __builtin_nontemporal_store(rt, &((vfloat4*)ret_out)[gi]);
    }
}

extern "C" void kernel_launch(void* const* d_in, const int* in_sizes, int n_in,
                              void* d_out, int out_size, void* d_ws, size_t ws_size,
                              hipStream_t stream) {
    const float* reward     = (const float*)d_in[0];
    const float* terminated = (const float*)d_in[1];
    const float* value      = (const float*)d_in[2];
    const float* next_value = (const float*)d_in[3];

    const int B = 8192;
    const int n_elem = B * T * 4;            // 8388608
    float* adv = (float*)d_out;
    float* ret = adv + n_elem;

    // 4 sequences per block -> 2048 blocks; 8 blocks/CU target.
    gae_scan_kernel<<<B / 4, 256, 0, stream>>>(reward, terminated, value,
                                               next_value, adv, ret);
}